// Round 9
// baseline (120.929 us; speedup 1.0000x reference)
//
#include <hip/hip_runtime.h>
#include <hip/hip_bf16.h>

#define VOCAB 100000
#define EMB   300
#define BATCH 2048
#define SEQ   256
#define NBLK1 1250   // 5000 waves x 20 rows (5 quads) = exactly 100000 rows

typedef float f4 __attribute__((ext_vector_type(4)));
typedef int   i4 __attribute__((ext_vector_type(4)));

// DIAGNOSTIC ROUND: kernel bodies identical to round 8 (27.07 us baseline).
// kernel_launch issues vocab_dot_kernel 6x (idempotent: p is rewritten with
// identical values each time; deterministic) then pool_sigmoid_kernel 1x.
// dur6 = 6*K1 + K2 + 6*gap  and  dur1 = K1 + K2 + gap = 27.07
//   =>  K1 + gap = (dur6 - 27.07) / 5
__global__ void __launch_bounds__(256) vocab_dot_kernel(
    const float* __restrict__ W, const float* __restrict__ fcw,
    float* __restrict__ p) {
  const int lane = threadIdx.x & 63;
  const int g    = lane >> 4;        // row within quad
  const int i    = lane & 15;        // lane within 16-lane group
  const int wave = (blockIdx.x * 256 + threadIdx.x) >> 6;  // 0..4999
  const int vb   = wave * 20 + g;    // this lane-group's rows: vb + 4k

  const f4* fcw4 = (const f4*)fcw;
  const f4 zero = {0.f, 0.f, 0.f, 0.f};
  const f4 w0 = fcw4[i];
  const f4 w1 = fcw4[i + 16];
  const f4 w2 = fcw4[i + 32];
  const f4 w3 = fcw4[i + 48];
  const f4 w4 = (i < 11) ? fcw4[i + 64] : zero;

  f4 A0, A1, A2, A3, A4, B0, B1, B2, B3, B4;

#define LOADQ(R0, R1, R2, R3, R4, row)                                  \
  {                                                                     \
    const f4* r = (const f4*)(W + (size_t)(row) * EMB);                 \
    R0 = __builtin_nontemporal_load(&r[i]);                             \
    R1 = __builtin_nontemporal_load(&r[i + 16]);                        \
    R2 = __builtin_nontemporal_load(&r[i + 32]);                        \
    R3 = __builtin_nontemporal_load(&r[i + 48]);                        \
    R4 = (i < 11) ? __builtin_nontemporal_load(&r[i + 64]) : zero;      \
  }

#define COMPQ(R0, R1, R2, R3, R4, row)                                  \
  {                                                                     \
    f4 s = R0 * w0 + R1 * w1 + R2 * w2 + R3 * w3 + R4 * w4;             \
    float acc = s.x + s.y + s.z + s.w;                                  \
    acc += __shfl_xor(acc, 8, 16);                                      \
    acc += __shfl_xor(acc, 4, 16);                                      \
    acc += __shfl_xor(acc, 2, 16);                                      \
    acc += __shfl_xor(acc, 1, 16);                                      \
    if (i == 0) p[row] = acc;                                           \
  }

  LOADQ(A0, A1, A2, A3, A4, vb + 0);
  LOADQ(B0, B1, B2, B3, B4, vb + 4);
  COMPQ(A0, A1, A2, A3, A4, vb + 0);
  LOADQ(A0, A1, A2, A3, A4, vb + 8);
  COMPQ(B0, B1, B2, B3, B4, vb + 4);
  LOADQ(B0, B1, B2, B3, B4, vb + 12);
  COMPQ(A0, A1, A2, A3, A4, vb + 8);
  LOADQ(A0, A1, A2, A3, A4, vb + 16);
  COMPQ(B0, B1, B2, B3, B4, vb + 12);
  COMPQ(A0, A1, A2, A3, A4, vb + 16);

#undef LOADQ
#undef COMPQ
}

// Kernel 2: out[b] = sigmoid( (sum_{l<len} p[tok[b,l]]) / len + fc_b )
__global__ void __launch_bounds__(256) pool_sigmoid_kernel(
    const int* __restrict__ tokens, const int* __restrict__ lengths,
    const float* __restrict__ p, const float* __restrict__ fcb,
    float* __restrict__ out) {
  const int lane = threadIdx.x & 63;
  const int w    = threadIdx.x >> 6;
  const int b    = blockIdx.x * 4 + w;

  const int len = lengths[b];
  const i4 t = ((const i4*)(tokens + (size_t)b * SEQ))[lane];
  const int base = lane * 4;

  float acc = 0.f;
  if (base + 0 < len) acc += p[t[0]];
  if (base + 1 < len) acc += p[t[1]];
  if (base + 2 < len) acc += p[t[2]];
  if (base + 3 < len) acc += p[t[3]];

  #pragma unroll
  for (int off = 32; off > 0; off >>= 1)
    acc += __shfl_down(acc, off, 64);

  if (lane == 0) {
    const float z = acc / (float)len + fcb[0];
    out[b] = 1.0f / (1.0f + expf(-z));
  }
}

extern "C" void kernel_launch(void* const* d_in, const int* in_sizes, int n_in,
                              void* d_out, int out_size, void* d_ws, size_t ws_size,
                              hipStream_t stream) {
  const int*   tokens  = (const int*)d_in[0];    // [B, L]
  const int*   lengths = (const int*)d_in[1];    // [B]
  const float* W_emb   = (const float*)d_in[2];  // [VOCAB, EMB]
  const float* fc_w    = (const float*)d_in[3];  // [1, EMB]
  const float* fc_b    = (const float*)d_in[4];  // [1]
  float* out = (float*)d_out;                    // [B, 1]
  float* p   = (float*)d_ws;                     // VOCAB floats (400 KB)

  // DIAGNOSTIC: 6 identical K1 launches (idempotent) to separate K1 time
  // from K2 + launch gap via dur6 vs the known dur1 = 27.07 us.
  for (int rep = 0; rep < 6; ++rep)
    vocab_dot_kernel<<<NBLK1, 256, 0, stream>>>(W_emb, fc_w, p);

  pool_sigmoid_kernel<<<BATCH / 4, 256, 0, stream>>>(
      tokens, lengths, p, fc_b, out);
}

// Round 10
// 54.046 us; speedup vs baseline: 2.2375x; 2.2375x over previous
//
#include <hip/hip_runtime.h>
#include <hip/hip_bf16.h>

#define VOCAB 100000
#define EMB   300
#define BATCH 2048
#define SEQ   256

typedef float f4 __attribute__((ext_vector_type(4)));

// Single item-major kernel: out[b] = sigmoid( (sum_{l<len} W[tok_bl]·w)/len + b )
// Uses commutativity: no per-row dot reduction needed — accumulate f4
// element-wise over all rows, one horizontal+cross-lane reduce at the end.
// Block b owns item b: 256 tokens staged in LDS; 16 groups of 16 lanes;
// group g gathers rows for tokens g, g+16, g+32, ... Each row = 75 float4:
// lane i reads f4 idx {i, i+16, i+32, i+48} (+ i+64 if i<11) -> coalesced.
// Plain (caching) loads on purpose: rows are re-touched 2.6x on average
// across the grid, so L2/L3 allocation turns 315 MB of demand into ~115 MB
// of HBM traffic.
__global__ void __launch_bounds__(256) item_pool_kernel(
    const int* __restrict__ tokens, const int* __restrict__ lengths,
    const float* __restrict__ W, const float* __restrict__ fcw,
    const float* __restrict__ fcb, float* __restrict__ out) {
  __shared__ int   stok[SEQ];
  __shared__ float spart[16];
  const int b   = blockIdx.x;
  const int tid = threadIdx.x;
  const int i   = tid & 15;        // lane within 16-lane group
  const int grp = tid >> 4;        // group 0..15 within block
  const int len = lengths[b];

  stok[tid] = tokens[(size_t)b * SEQ + tid];   // coalesced 1 KB/block
  __syncthreads();

  const f4* fcw4 = (const f4*)fcw;
  const f4 zero = {0.f, 0.f, 0.f, 0.f};
  const f4 w0 = fcw4[i];
  const f4 w1 = fcw4[i + 16];
  const f4 w2 = fcw4[i + 32];
  const f4 w3 = fcw4[i + 48];
  const f4 w4 = (i < 11) ? fcw4[i + 64] : zero;

  // Tokens for this group: grp + 16*j, j in [0, nmine)
  const int nmine = (len > grp) ? ((len - grp + 15) >> 4) : 0;

  f4 acc = zero;
  if (nmine > 0) {
    const f4* r = (const f4*)(W + (size_t)stok[grp] * EMB);
    f4 A0 = r[i], A1 = r[i + 16], A2 = r[i + 32], A3 = r[i + 48];
    f4 A4 = (i < 11) ? r[i + 64] : zero;
    #pragma unroll 2
    for (int j = 1; j < nmine; ++j) {
      const f4* r2 = (const f4*)(W + (size_t)stok[grp + (j << 4)] * EMB);
      f4 B0 = r2[i], B1 = r2[i + 16], B2 = r2[i + 32], B3 = r2[i + 48];
      f4 B4 = (i < 11) ? r2[i + 64] : zero;
      acc += A0 * w0 + A1 * w1 + A2 * w2 + A3 * w3 + A4 * w4;
      A0 = B0; A1 = B1; A2 = B2; A3 = B3; A4 = B4;
    }
    acc += A0 * w0 + A1 * w1 + A2 * w2 + A3 * w3 + A4 * w4;
  }

  // Reduce: horizontal f4 -> 16-lane group -> 16 group partials -> scalar.
  float s = acc.x + acc.y + acc.z + acc.w;
  s += __shfl_xor(s, 8, 16);
  s += __shfl_xor(s, 4, 16);
  s += __shfl_xor(s, 2, 16);
  s += __shfl_xor(s, 1, 16);
  if (i == 0) spart[grp] = s;
  __syncthreads();
  if (tid == 0) {
    float t = 0.f;
    #pragma unroll
    for (int k = 0; k < 16; ++k) t += spart[k];
    const float z = t / (float)len + fcb[0];
    out[b] = 1.0f / (1.0f + expf(-z));
  }
}

extern "C" void kernel_launch(void* const* d_in, const int* in_sizes, int n_in,
                              void* d_out, int out_size, void* d_ws, size_t ws_size,
                              hipStream_t stream) {
  const int*   tokens  = (const int*)d_in[0];    // [B, L]
  const int*   lengths = (const int*)d_in[1];    // [B]
  const float* W_emb   = (const float*)d_in[2];  // [VOCAB, EMB]
  const float* fc_w    = (const float*)d_in[3];  // [1, EMB]
  const float* fc_b    = (const float*)d_in[4];  // [1]
  float* out = (float*)d_out;                    // [B, 1]

  // One block per item, one dispatch, no workspace, no barrier.
  item_pool_kernel<<<BATCH, 256, 0, stream>>>(
      tokens, lengths, W_emb, fc_w, fc_b, out);
}

// Round 11
// 27.376 us; speedup vs baseline: 4.4173x; 1.9742x over previous
//
#include <hip/hip_runtime.h>
#include <hip/hip_bf16.h>

#define VOCAB 100000
#define EMB   300
#define BATCH 2048
#define SEQ   256
#define NBLK1 1250   // 5000 waves x 20 rows (5 quads) = exactly 100000 rows

typedef float f4 __attribute__((ext_vector_type(4)));

// Kernel 1 (UNCHANGED from round 8 — measured at K1+gap = 18.77 us warm):
// p[v] = dot(W_emb[v,:], fc_w). 16 lanes/row, 5 quads/wave, zero tail,
// ping-pong 2-deep load pipeline, nt loads.
__global__ void __launch_bounds__(256) vocab_dot_kernel(
    const float* __restrict__ W, const float* __restrict__ fcw,
    float* __restrict__ p) {
  const int lane = threadIdx.x & 63;
  const int g    = lane >> 4;        // row within quad
  const int i    = lane & 15;        // lane within 16-lane group
  const int wave = (blockIdx.x * 256 + threadIdx.x) >> 6;  // 0..4999
  const int vb   = wave * 20 + g;    // this lane-group's rows: vb + 4k

  const f4* fcw4 = (const f4*)fcw;
  const f4 zero = {0.f, 0.f, 0.f, 0.f};
  const f4 w0 = fcw4[i];
  const f4 w1 = fcw4[i + 16];
  const f4 w2 = fcw4[i + 32];
  const f4 w3 = fcw4[i + 48];
  const f4 w4 = (i < 11) ? fcw4[i + 64] : zero;

  f4 A0, A1, A2, A3, A4, B0, B1, B2, B3, B4;

#define LOADQ(R0, R1, R2, R3, R4, row)                                  \
  {                                                                     \
    const f4* r = (const f4*)(W + (size_t)(row) * EMB);                 \
    R0 = __builtin_nontemporal_load(&r[i]);                             \
    R1 = __builtin_nontemporal_load(&r[i + 16]);                        \
    R2 = __builtin_nontemporal_load(&r[i + 32]);                        \
    R3 = __builtin_nontemporal_load(&r[i + 48]);                        \
    R4 = (i < 11) ? __builtin_nontemporal_load(&r[i + 64]) : zero;      \
  }

#define COMPQ(R0, R1, R2, R3, R4, row)                                  \
  {                                                                     \
    f4 s = R0 * w0 + R1 * w1 + R2 * w2 + R3 * w3 + R4 * w4;             \
    float acc = s.x + s.y + s.z + s.w;                                  \
    acc += __shfl_xor(acc, 8, 16);                                      \
    acc += __shfl_xor(acc, 4, 16);                                      \
    acc += __shfl_xor(acc, 2, 16);                                      \
    acc += __shfl_xor(acc, 1, 16);                                      \
    if (i == 0) p[row] = acc;                                           \
  }

  LOADQ(A0, A1, A2, A3, A4, vb + 0);
  LOADQ(B0, B1, B2, B3, B4, vb + 4);
  COMPQ(A0, A1, A2, A3, A4, vb + 0);
  LOADQ(A0, A1, A2, A3, A4, vb + 8);
  COMPQ(B0, B1, B2, B3, B4, vb + 4);
  LOADQ(B0, B1, B2, B3, B4, vb + 12);
  COMPQ(A0, A1, A2, A3, A4, vb + 8);
  LOADQ(A0, A1, A2, A3, A4, vb + 16);
  COMPQ(B0, B1, B2, B3, B4, vb + 12);
  COMPQ(A0, A1, A2, A3, A4, vb + 16);

#undef LOADQ
#undef COMPQ
}

// Kernel 2: out[b] = sigmoid( (sum_{l<len} p[tok[b,l]]) / len + fc_b )
// Block-per-item, 256 threads: thread t handles token t — one coalesced
// token load + ONE gather (4x shorter dependent chain than int4 variant),
// 8192 waves (4x the occupancy). Two-level reduce: shfl within wave,
// LDS partials across the 4 waves.
__global__ void __launch_bounds__(256) pool_sigmoid_kernel(
    const int* __restrict__ tokens, const int* __restrict__ lengths,
    const float* __restrict__ p, const float* __restrict__ fcb,
    float* __restrict__ out) {
  __shared__ float part[4];
  const int b   = blockIdx.x;
  const int t   = threadIdx.x;
  const int len = lengths[b];

  // Issue token load immediately; gather as soon as it lands.
  const int tok = tokens[(size_t)b * SEQ + t];
  float acc = (t < len) ? p[tok] : 0.f;

  #pragma unroll
  for (int off = 32; off > 0; off >>= 1)
    acc += __shfl_down(acc, off, 64);

  const int lane = t & 63, w = t >> 6;
  if (lane == 0) part[w] = acc;
  __syncthreads();
  if (t == 0) {
    const float s = part[0] + part[1] + part[2] + part[3];
    const float z = s / (float)len + fcb[0];
    out[b] = 1.0f / (1.0f + expf(-z));
  }
}

extern "C" void kernel_launch(void* const* d_in, const int* in_sizes, int n_in,
                              void* d_out, int out_size, void* d_ws, size_t ws_size,
                              hipStream_t stream) {
  const int*   tokens  = (const int*)d_in[0];    // [B, L]
  const int*   lengths = (const int*)d_in[1];    // [B]
  const float* W_emb   = (const float*)d_in[2];  // [VOCAB, EMB]
  const float* fc_w    = (const float*)d_in[3];  // [1, EMB]
  const float* fc_b    = (const float*)d_in[4];  // [1]
  float* out = (float*)d_out;                    // [B, 1]
  float* p   = (float*)d_ws;                     // VOCAB floats (400 KB)

  // Kernel 1: 1250 blocks, 20 rows/wave, zero tail (measured 18.77 us incl gap).
  vocab_dot_kernel<<<NBLK1, 256, 0, stream>>>(W_emb, fc_w, p);

  // Kernel 2: one block per item, one gather per thread.
  pool_sigmoid_kernel<<<BATCH, 256, 0, stream>>>(
      tokens, lengths, p, fc_b, out);
}